// Round 5
// baseline (65.801 us; speedup 1.0000x reference)
//
#include <hip/hip_runtime.h>

// ConvLogicTreeLayer: B=16, C_in=64, H=W=32, C_out=128, K=3, PAD=1, TREE_DEPTH=3
// Refold: softmax mixture of the 16 logic ops is affine in {1,a,b,ab} ->
// 4 coeffs per (o,gate); only gates 0..3 used (L0: 0-3, L1: 1-2, L2: 3).
// This version: single-wave blocks (64 thr), 8 px/thread, aligned 16B loads,
// +-1 column via shuffles, non-temporal output stores (native vec type).

#define C_OUT 128
#define C_IN  64
#define HW    32

typedef float f32x4 __attribute__((ext_vector_type(4)));

__device__ __forceinline__ void gate8(const float4 c, const float* a,
                                      const float* b, float* r) {
    #pragma unroll
    for (int i = 0; i < 8; ++i)
        r[i] = fmaf(a[i] * b[i], c.w, fmaf(a[i], c.y, fmaf(b[i], c.z, c.x)));
}

// Load 8 horizontally-consecutive pixels of plane c, row h+dy, cols 8q+dx..+7.
// Aligned vec4 loads; dx=+-1 tap comes from neighbor lane via shuffle.
__device__ __forceinline__ void load_leaf(const float* __restrict__ xb,
                                          int c, int dy, int dx,
                                          int h, int q, float* t) {
    int hh = h + dy;
    bool hok = ((unsigned)hh < HW);
    const float* rp = xb + (c * HW + (hok ? hh : 0)) * HW + 8 * q;
    float4 e0 = *(const float4*)rp;        // 32B-aligned
    float4 e1 = *(const float4*)(rp + 4);
    float prev = __shfl_up(e1.w, 1);       // lane-1's col 8q-1
    float next = __shfl_down(e0.x, 1);     // lane+1's col 8q+8
    float e[8] = {e0.x, e0.y, e0.z, e0.w, e1.x, e1.y, e1.z, e1.w};
    float s[8];
    if (dx == 0) {                          // block-uniform branches
        #pragma unroll
        for (int i = 0; i < 8; ++i) s[i] = e[i];
    } else if (dx < 0) {
        s[0] = (q > 0) ? prev : 0.f;
        #pragma unroll
        for (int i = 1; i < 8; ++i) s[i] = e[i - 1];
    } else {
        #pragma unroll
        for (int i = 0; i < 7; ++i) s[i] = e[i + 1];
        s[7] = (q < 3) ? next : 0.f;
    }
    #pragma unroll
    for (int i = 0; i < 8; ++i) t[i] = hok ? s[i] : 0.f;
}

// One block = one wave; covers a 16-row half of one (b,o) image.
__global__ __launch_bounds__(64) void logic_tree_fused(
    const float* __restrict__ x, const float* __restrict__ wts,
    const int* __restrict__ leaf_idx, float* __restrict__ out)
{
    const int blk  = blockIdx.x;            // 0..4095 == ((b*128+o)<<1)|half
    const int half = blk & 1;
    const int o    = (blk >> 1) & (C_OUT - 1);
    const int b    = blk >> 8;

    __shared__ float4 cf_s[4];
    if (threadIdx.x < 4) {
        const int g = threadIdx.x;
        const float* wp = wts + (o * 7 + g) * 16;
        float v[16];
        float m = -1e30f;
        #pragma unroll
        for (int i = 0; i < 16; ++i) { v[i] = wp[i]; m = fmaxf(m, v[i]); }
        float s = 0.f;
        #pragma unroll
        for (int i = 0; i < 16; ++i) { v[i] = expf(v[i] - m); s += v[i]; }
        float inv = 1.f / s;
        #pragma unroll
        for (int i = 0; i < 16; ++i) v[i] *= inv;
        // ops in {1,a,b,ab}: 0:0 1:ab 2:a-ab 3:a 4:b-ab 5:b 6:a+b-2ab 7:a+b-ab
        // 8:1-(a+b-ab) 9:1-(a+b-2ab) 10:1-b 11:1-b+ab 12:1-a 13:1-a+ab 14:1-ab 15:1
        float c0  = v[8]+v[9]+v[10]+v[11]+v[12]+v[13]+v[14]+v[15];
        float ca  = v[2]+v[3]+v[6]+v[7]-v[8]-v[9]-v[12]-v[13];
        float cb  = v[4]+v[5]+v[6]+v[7]-v[8]-v[9]-v[10]-v[11];
        float cab = v[1]-v[2]-v[4]-2.f*v[6]-v[7]+v[8]+2.f*v[9]+v[11]+v[13]-v[14];
        cf_s[g] = make_float4(c0, ca, cb, cab);
    }

    int cch[8], dy[8], dxx[8];
    #pragma unroll
    for (int j = 0; j < 8; ++j) {
        int li = leaf_idx[o * 8 + j];      // block-uniform -> s_load
        int c = li / 9;
        int kk = li - c * 9;
        int ky = kk / 3;
        cch[j] = c; dy[j] = ky - 1; dxx[j] = (kk - ky * 3) - 1;
    }
    __syncthreads();

    const int q = threadIdx.x & 3;               // w = 8q..8q+7
    const int h = half * 16 + (threadIdx.x >> 2); // row
    const float* xb = x + (size_t)b * C_IN * HW * HW;

    const float4 cf0 = cf_s[0], cf1 = cf_s[1], cf2 = cf_s[2], cf3 = cf_s[3];
    float la[8], lb[8], p0[8], p1[8], q0[8], q1[8], r[8];

    load_leaf(xb, cch[0], dy[0], dxx[0], h, q, la);
    load_leaf(xb, cch[1], dy[1], dxx[1], h, q, lb);
    gate8(cf0, la, lb, p0);
    load_leaf(xb, cch[2], dy[2], dxx[2], h, q, la);
    load_leaf(xb, cch[3], dy[3], dxx[3], h, q, lb);
    gate8(cf1, la, lb, p1);
    gate8(cf1, p0, p1, q0);
    load_leaf(xb, cch[4], dy[4], dxx[4], h, q, la);
    load_leaf(xb, cch[5], dy[5], dxx[5], h, q, lb);
    gate8(cf2, la, lb, p0);
    load_leaf(xb, cch[6], dy[6], dxx[6], h, q, la);
    load_leaf(xb, cch[7], dy[7], dxx[7], h, q, lb);
    gate8(cf3, la, lb, p1);
    gate8(cf2, p0, p1, q1);
    gate8(cf3, q0, q1, r);

    float* op = out + ((size_t)(b * C_OUT + o) * (HW * HW)) + h * HW + 8 * q;
    f32x4 v0 = {r[0], r[1], r[2], r[3]};
    f32x4 v1 = {r[4], r[5], r[6], r[7]};
    __builtin_nontemporal_store(v0, (f32x4*)op);
    __builtin_nontemporal_store(v1, (f32x4*)(op + 4));
}

extern "C" void kernel_launch(void* const* d_in, const int* in_sizes, int n_in,
                              void* d_out, int out_size, void* d_ws, size_t ws_size,
                              hipStream_t stream) {
    const float* x       = (const float*)d_in[0];
    const float* weights = (const float*)d_in[1];
    const int*   leaves  = (const int*)d_in[2];
    float* out = (float*)d_out;
    logic_tree_fused<<<16 * C_OUT * 2, 64, 0, stream>>>(x, weights, leaves, out);
}